// Round 16
// baseline (305.836 us; speedup 1.0000x reference)
//
#include <hip/hip_runtime.h>

#define BB 16384
#define SS 200
#define NF 6
#define HH 50
#define TT 5
#define ROWS 32          // 2 N-tiles x 16 rows
#define BLK 832          // 13 waves, one per M-tile
#define SEQ_STRIDE (SS * NF)   // 1200

typedef _Float16 half8 __attribute__((ext_vector_type(8)));
typedef __attribute__((ext_vector_type(4))) float f32x4;

#define LOG2E 1.44269504088896f

__device__ __forceinline__ unsigned short h_bits(_Float16 h) {
    return __builtin_bit_cast(unsigned short, h);
}
__device__ __forceinline__ float h_f(unsigned short b) {
    return (float)__builtin_bit_cast(_Float16, b);
}

// A fragment for 8 consecutive k of one gate-row, pre-scaled; k==56 carries the
// fused bias (B[56][*] fixed at 1.0 -> bias arrives through the MFMA).
__device__ __forceinline__ half8 mk8(const float* __restrict__ Wih,
                                     const float* __restrict__ Whh,
                                     const float* __restrict__ bih,
                                     const float* __restrict__ bhh,
                                     bool valid, int orow, float sc, int kbase)
{
    half8 r;
    #pragma unroll
    for (int j = 0; j < 8; ++j) {
        int k = kbase + j;
        float v = 0.0f;
        if (valid) {
            if (k < NF)            v = Wih[orow * NF + k];
            else if (k < NF + HH)  v = Whh[orow * HH + (k - NF)];
            else if (k == NF + HH) v = bih[orow] + bhh[orow];
        }
        r[j] = (_Float16)(v * sc);
    }
    return r;
}

// acc is directly the exp2 argument (weights/bias pre-scaled).
__device__ __forceinline__ void cell_upd(const f32x4& g, float& c, bool real,
                                         int posQ, unsigned short* BQ)
{
    float si = __builtin_amdgcn_rcpf(1.0f + __builtin_amdgcn_exp2f(g[0]));
    float sf = __builtin_amdgcn_rcpf(1.0f + __builtin_amdgcn_exp2f(g[1]));
    float tg = fmaf(2.0f, __builtin_amdgcn_rcpf(1.0f + __builtin_amdgcn_exp2f(g[2])), -1.0f);
    float so = __builtin_amdgcn_rcpf(1.0f + __builtin_amdgcn_exp2f(g[3]));
    float cc = sf * c + si * tg;
    c = cc;
    float tc = fmaf(2.0f, __builtin_amdgcn_rcpf(1.0f +
                    __builtin_amdgcn_exp2f(-2.0f * LOG2E * cc)), -1.0f);
    float hh = so * tc;
    if (real) BQ[posQ] = h_bits((_Float16)hh);
}

#define MFMA16(acc, a, b) acc = __builtin_amdgcn_mfma_f32_16x16x32_f16(a, b, acc, 0, 0, 0)

__global__ __launch_bounds__(BLK, 7) void lstm_13w(
    const float* __restrict__ seq,
    const float* __restrict__ Wih_e, const float* __restrict__ Whh_e,
    const float* __restrict__ bih_e, const float* __restrict__ bhh_e,
    const float* __restrict__ Wih_d, const float* __restrict__ Whh_d,
    const float* __restrict__ bih_d, const float* __restrict__ bhh_d,
    const float* __restrict__ Wl, const float* __restrict__ bl,
    float* __restrict__ out)
{
    // B state: 2 buffers x 2 N-tiles x 128 chunks (16B) = 8KB
    __shared__ half8 Bsh8[512];
    __shared__ float xs[ROWS * 97];         // 16 steps x 6 feats per row (12.4KB)
    __shared__ float Wls[NF * HH];
    __shared__ float bls[NF];

    unsigned short* Bu = (unsigned short*)Bsh8;   // buffer b at ushort ofs b*2048

    const int tid  = threadIdx.x;
    const int w    = tid >> 6;              // wave = M-tile (0..12)
    const int lane = tid & 63;
    const int q    = lane >> 4;
    const int l15  = lane & 15;
    const int b0   = blockIdx.x * ROWS;

    // per-lane A-row descriptor (lane q*16+l15 holds A[w*16+l15][ks*32+q*8+j])
    const int g2 = w * 16 + l15, ur = g2 >> 2, gt = g2 & 3;
    const bool vA = (ur < HH);
    const int orow = gt * HH + ur;
    const float sc = (gt == 2) ? -2.0f * LOG2E : -LOG2E;

    // cell ownership: unit u = w*4+q, rows l15 (N-tile 0) and 16+l15 (N-tile 1)
    const int u = w * 4 + q;
    const bool real = (u < HH);
    const int hk = NF + u;
    const int hposX = (((hk >> 5) * 64) + ((hk >> 3) & 3) * 16 + l15) * 8 + (hk & 7);
    const int hposY = hposX + 1024;         // N-tile 1 matrix

    // ---- one-time init ----
    for (int i = tid; i < 512; i += BLK) Bsh8[i] = (half8)(_Float16)0.0f;
    for (int i = tid; i < NF * HH; i += BLK) Wls[i] = Wl[i];
    if (tid < NF) bls[tid] = bl[tid];
    for (int idx = tid; idx < ROWS * 96; idx += BLK) {
        int row = idx / 96, cc = idx - row * 96;
        xs[row * 97 + cc] = seq[(size_t)(b0 + row) * SEQ_STRIDE + cc];
    }
    __syncthreads();
    // bias lane k=56 = 1.0 in both buffers x both N-tiles (never overwritten)
    if (tid < 64) {
        int buf = tid >> 5, nt = (tid >> 4) & 1, lr = tid & 15;
        Bu[buf * 2048 + nt * 1024 + (112 + lr) * 8] = h_bits((_Float16)1.0f);
    }
    // x_0 into buf0 (h-slots zero = h0)
    if (tid < 192) {
        int row = tid & 31, n = tid >> 5;
        Bu[(row >> 4) * 1024 + (row & 15) * 8 + n] = h_bits((_Float16)xs[row * 97 + n]);
    }
    __syncthreads();

    half8 a0 = mk8(Wih_e, Whh_e, bih_e, bhh_e, vA, orow, sc, q * 8);
    half8 a1 = mk8(Wih_e, Whh_e, bih_e, bhh_e, vA, orow, sc, 32 + q * 8);
    float cX = 0.0f, cY = 0.0f;

    // ==== encoder: 12 chunks of 16 steps ====
    for (int t0 = 0; t0 < 192; t0 += 16) {
        #pragma unroll
        for (int k = 0; k < 16; ++k) {
            const int P8 = (k & 1) * 256;                 // half8 chunk base
            unsigned short* BQ = Bu + ((k & 1) ^ 1) * 2048;

            half8 bX0 = Bsh8[P8 + lane];
            half8 bX1 = Bsh8[P8 + 64 + lane];
            half8 bY0 = Bsh8[P8 + 128 + lane];
            half8 bY1 = Bsh8[P8 + 192 + lane];
            f32x4 accX = {0.f, 0.f, 0.f, 0.f};
            f32x4 accY = {0.f, 0.f, 0.f, 0.f};
            MFMA16(accX, a0, bX0); MFMA16(accX, a1, bX1);
            MFMA16(accY, a0, bY0); MFMA16(accY, a1, bY1);

            if (k == 15) {
                __syncthreads();           // prior xs reads complete
                const int tn = t0 + 16;    // refresh xs for steps tn .. tn+15
                for (int idx = tid; idx < ROWS * 96; idx += BLK) {
                    int row = idx / 96, cc = idx - row * 96;
                    float v = 0.0f;
                    if (tn + cc / 6 < SS)
                        v = seq[(size_t)(b0 + row) * SEQ_STRIDE + tn * NF + cc];
                    xs[row * 97 + cc] = v;
                }
                __syncthreads();           // new chunk visible
            }
            // x_{t+1} (compile-time slot) into Q
            if (tid < 192) {
                int row = tid & 31, n = tid >> 5;
                BQ[(row >> 4) * 1024 + (row & 15) * 8 + n] =
                    h_bits((_Float16)xs[row * 97 + ((k + 1) & 15) * NF + n]);
            }
            cell_upd(accX, cX, real, hposX, BQ);
            cell_upd(accY, cY, real, hposY, BQ);
            __syncthreads();               // Q complete for next step
        }
    }

    // ==== encoder tail: t = 192..199 (xs slots 0..7) ====
    #pragma unroll
    for (int k = 0; k < 8; ++k) {
        const int P8 = (k & 1) * 256;
        unsigned short* BQ = Bu + ((k & 1) ^ 1) * 2048;

        half8 bX0 = Bsh8[P8 + lane];
        half8 bX1 = Bsh8[P8 + 64 + lane];
        half8 bY0 = Bsh8[P8 + 128 + lane];
        half8 bY1 = Bsh8[P8 + 192 + lane];
        f32x4 accX = {0.f, 0.f, 0.f, 0.f};
        f32x4 accY = {0.f, 0.f, 0.f, 0.f};
        MFMA16(accX, a0, bX0); MFMA16(accX, a1, bX1);
        MFMA16(accY, a0, bY0); MFMA16(accY, a1, bY1);

        const int slot = (k < 7) ? (k + 1) : 7;   // t=199 writes dec_in = x_199
        if (tid < 192) {
            int row = tid & 31, n = tid >> 5;
            BQ[(row >> 4) * 1024 + (row & 15) * 8 + n] =
                h_bits((_Float16)xs[row * 97 + slot * NF + n]);
        }
        cell_upd(accX, cX, real, hposX, BQ);
        cell_upd(accY, cY, real, hposY, BQ);
        __syncthreads();
    }

    // ==== switch to decoder weights (registers only) ====
    a0 = mk8(Wih_d, Whh_d, bih_d, bhh_d, vA, orow, sc, q * 8);
    a1 = mk8(Wih_d, Whh_d, bih_d, bhh_d, vA, orow, sc, 32 + q * 8);

    // ==== decoder: 5 steps ====
    #pragma unroll
    for (int d = 0; d < TT; ++d) {
        const int P8 = (d & 1) * 256;
        unsigned short* BQ = Bu + ((d & 1) ^ 1) * 2048;

        half8 bX0 = Bsh8[P8 + lane];
        half8 bX1 = Bsh8[P8 + 64 + lane];
        half8 bY0 = Bsh8[P8 + 128 + lane];
        half8 bY1 = Bsh8[P8 + 192 + lane];
        f32x4 accX = {0.f, 0.f, 0.f, 0.f};
        f32x4 accY = {0.f, 0.f, 0.f, 0.f};
        MFMA16(accX, a0, bX0); MFMA16(accX, a1, bX1);
        MFMA16(accY, a0, bY0); MFMA16(accY, a1, bY1);
        cell_upd(accX, cX, real, hposX, BQ);
        cell_upd(accY, cY, real, hposY, BQ);
        __syncthreads();                   // h_t visible in Q

        if (tid < 192) {
            int row = tid & 31, n = tid >> 5;
            int nt = row >> 4, lr = row & 15;
            float a = bls[n];
            #pragma unroll
            for (int u2 = 0; u2 < HH; ++u2) {
                int kk = NF + u2;
                int pos = nt * 1024
                        + ((kk >> 5) * 64 + ((kk >> 3) & 3) * 16 + lr) * 8 + (kk & 7);
                a = fmaf(Wls[n * HH + u2], h_f(BQ[pos]), a);
            }
            out[(size_t)(b0 + row) * (TT * NF) + d * NF + n] = a;
            BQ[nt * 1024 + lr * 8 + n] = h_bits((_Float16)a);   // next x
        }
        __syncthreads();
    }
}

extern "C" void kernel_launch(void* const* d_in, const int* in_sizes, int n_in,
                              void* d_out, int out_size, void* d_ws, size_t ws_size,
                              hipStream_t stream)
{
    const float* seq   = (const float*)d_in[0];
    const float* Wih_e = (const float*)d_in[1];
    const float* Whh_e = (const float*)d_in[2];
    const float* bih_e = (const float*)d_in[3];
    const float* bhh_e = (const float*)d_in[4];
    const float* Wih_d = (const float*)d_in[5];
    const float* Whh_d = (const float*)d_in[6];
    const float* bih_d = (const float*)d_in[7];
    const float* bhh_d = (const float*)d_in[8];
    const float* Wl    = (const float*)d_in[9];
    const float* bl    = (const float*)d_in[10];
    float* out = (float*)d_out;

    dim3 grid(BB / ROWS);   // 512 blocks -> 2 per CU = 26 waves/CU, single pass
    dim3 block(BLK);        // 13 waves, one M-tile each (perfect balance)
    lstm_13w<<<grid, block, 0, stream>>>(seq, Wih_e, Whh_e, bih_e, bhh_e,
                                         Wih_d, Whh_d, bih_d, bhh_d,
                                         Wl, bl, out);
}

// Round 17
// 252.629 us; speedup vs baseline: 1.2106x; 1.2106x over previous
//
#include <hip/hip_runtime.h>

#define BB 16384
#define SS 200
#define NF 6
#define HH 50
#define TT 5
#define ROWS 16
#define BLK 256          // 4 waves; each lands on a different SIMD
#define SEQ_STRIDE (SS * NF)   // 1200
#define NTM 4            // max tiles/wave: wave0 {0,4,8,12}, wave w {w,w+4,w+8}

typedef _Float16 half8 __attribute__((ext_vector_type(8)));
typedef __attribute__((ext_vector_type(4))) float f32x4;

#define LOG2E 1.44269504088896f

__device__ __forceinline__ unsigned short h_bits(_Float16 h) {
    return __builtin_bit_cast(unsigned short, h);
}
__device__ __forceinline__ float h_f(unsigned short b) {
    return (float)__builtin_bit_cast(_Float16, b);
}

// A fragment for 8 consecutive k of one gate-row, pre-scaled; k==56 carries the
// fused bias (B[56][*] fixed at 1.0 -> bias arrives through the MFMA).
__device__ __forceinline__ half8 mk8(const float* __restrict__ Wih,
                                     const float* __restrict__ Whh,
                                     const float* __restrict__ bih,
                                     const float* __restrict__ bhh,
                                     bool valid, int orow, float sc, int kbase)
{
    half8 r;
    #pragma unroll
    for (int j = 0; j < 8; ++j) {
        int k = kbase + j;
        float v = 0.0f;
        if (valid) {
            if (k < NF)            v = Wih[orow * NF + k];
            else if (k < NF + HH)  v = Whh[orow * HH + (k - NF)];
            else if (k == NF + HH) v = bih[orow] + bhh[orow];
        }
        r[j] = (_Float16)(v * sc);
    }
    return r;
}

// acc is directly the exp2 argument (weights/bias pre-scaled).
__device__ __forceinline__ void cell_upd(const f32x4& g, float& c, bool real,
                                         int posQ, unsigned short* BQ)
{
    float si = __builtin_amdgcn_rcpf(1.0f + __builtin_amdgcn_exp2f(g[0]));
    float sf = __builtin_amdgcn_rcpf(1.0f + __builtin_amdgcn_exp2f(g[1]));
    float tg = fmaf(2.0f, __builtin_amdgcn_rcpf(1.0f + __builtin_amdgcn_exp2f(g[2])), -1.0f);
    float so = __builtin_amdgcn_rcpf(1.0f + __builtin_amdgcn_exp2f(g[3]));
    float cc = sf * c + si * tg;
    c = cc;
    float tc = fmaf(2.0f, __builtin_amdgcn_rcpf(1.0f +
                    __builtin_amdgcn_exp2f(-2.0f * LOG2E * cc)), -1.0f);
    float hh = so * tc;
    if (real) BQ[posQ] = h_bits((_Float16)hh);
}

__global__ __launch_bounds__(BLK, 4) void lstm_4w(
    const float* __restrict__ seq,
    const float* __restrict__ Wih_e, const float* __restrict__ Whh_e,
    const float* __restrict__ bih_e, const float* __restrict__ bhh_e,
    const float* __restrict__ Wih_d, const float* __restrict__ Whh_d,
    const float* __restrict__ bih_d, const float* __restrict__ bhh_d,
    const float* __restrict__ Wl, const float* __restrict__ bl,
    float* __restrict__ out)
{
    __shared__ half8 Bsh8[256];             // 2 buffers x 128 chunks (2KB each)
    __shared__ float xs[ROWS * 97];         // 16 steps x 6 feats per row
    __shared__ float Wls[NF * HH];
    __shared__ float bls[NF];

    unsigned short* Bu = (unsigned short*)Bsh8;   // buffer b at ushort ofs b*1024

    const int tid  = threadIdx.x;
    const int w    = tid >> 6;              // 4 waves
    const int lane = tid & 63;
    const int q    = lane >> 4;
    const int l15  = lane & 15;
    const int b0   = blockIdx.x * ROWS;
    const int nt   = (w == 0) ? 4 : 3;      // wave0: {0,4,8,12}; w: {w,w+4,w+8}
    const int xid  = tid - 160;             // x-write duty on waves 2-3

    // ---- per-tile A descriptors + constants ----
    half8 a0[NTM], a1[NTM];
    float cst[NTM];
    int   hpos[NTM];
    bool  realu[NTM];
    int   orow_[NTM];
    bool  vA_[NTM];
    float sc_[NTM];
    #pragma unroll
    for (int i = 0; i < NTM; ++i) {
        cst[i] = 0.0f;
        if (i < nt) {
            int tile = (i < 3) ? (w + i * 4) : 12;
            int g2 = tile * 16 + l15, ur = g2 >> 2, gt = g2 & 3;
            vA_[i] = (ur < HH);
            orow_[i] = gt * HH + ur;
            sc_[i] = (gt == 2) ? -2.0f * LOG2E : -LOG2E;
            int uu = tile * 4 + q, k = NF + uu;
            hpos[i] = (((k >> 5) * 64) + ((k >> 3) & 3) * 16 + l15) * 8 + (k & 7);
            realu[i] = (uu < HH);
        }
    }

    // ---- one-time init ----
    for (int i = tid; i < 256; i += BLK) Bsh8[i] = (half8)(_Float16)0.0f;
    for (int i = tid; i < NF * HH; i += BLK) Wls[i] = Wl[i];
    if (tid < NF) bls[tid] = bl[tid];
    for (int idx = tid; idx < ROWS * 96; idx += BLK) {
        int row = idx / 96, cc = idx - row * 96;
        xs[row * 97 + cc] = seq[(size_t)(b0 + row) * SEQ_STRIDE + cc];
    }
    __syncthreads();
    // bias lane k=56 = 1.0 in both buffers (never overwritten: x k<6, h 6..55)
    if (tid < 16) {
        Bu[(112 + tid) * 8]        = h_bits((_Float16)1.0f);
        Bu[1024 + (112 + tid) * 8] = h_bits((_Float16)1.0f);
    }
    // x_0 into buf0 (h-slots zero = h0)
    if (tid < 96) {
        int row = tid & 15, n = tid >> 4;
        Bu[row * 8 + n] = h_bits((_Float16)xs[row * 97 + n]);
    }
    __syncthreads();

    #pragma unroll
    for (int i = 0; i < NTM; ++i) if (i < nt) {
        a0[i] = mk8(Wih_e, Whh_e, bih_e, bhh_e, vA_[i], orow_[i], sc_[i], q * 8);
        a1[i] = mk8(Wih_e, Whh_e, bih_e, bhh_e, vA_[i], orow_[i], sc_[i], 32 + q * 8);
    }

    // ==== encoder: 12 chunks of 16 steps; 1 barrier/step ====
    for (int t0 = 0; t0 < 192; t0 += 16) {
        #pragma unroll
        for (int k = 0; k < 16; ++k) {
            const int P8 = (k & 1) * 128;
            unsigned short* BQ = Bu + ((k & 1) ^ 1) * 1024;

            half8 bh0 = Bsh8[P8 + lane];
            half8 bh1 = Bsh8[P8 + 64 + lane];
            f32x4 acc[NTM];
            #pragma unroll
            for (int i = 0; i < NTM; ++i) if (i < nt) {
                acc[i] = (f32x4){0.f, 0.f, 0.f, 0.f};
                acc[i] = __builtin_amdgcn_mfma_f32_16x16x32_f16(a0[i], bh0, acc[i], 0, 0, 0);
            }
            #pragma unroll
            for (int i = 0; i < NTM; ++i) if (i < nt)
                acc[i] = __builtin_amdgcn_mfma_f32_16x16x32_f16(a1[i], bh1, acc[i], 0, 0, 0);

            if (k == 15) {
                __syncthreads();           // prior xs reads complete
                const int tn = t0 + 16;    // refresh xs for steps tn .. tn+15
                for (int idx = tid; idx < ROWS * 96; idx += BLK) {
                    int row = idx / 96, cc = idx - row * 96;
                    float v = 0.0f;
                    if (tn + cc / 6 < SS)
                        v = seq[(size_t)(b0 + row) * SEQ_STRIDE + tn * NF + cc];
                    xs[row * 97 + cc] = v;
                }
                __syncthreads();           // new chunk visible
            }
            // x_{t+1} (compile-time slot) into Q — waves 2-3
            if (xid >= 0 && xid < 96) {
                int row = xid & 15, n = xid >> 4;
                BQ[row * 8 + n] =
                    h_bits((_Float16)xs[row * 97 + ((k + 1) & 15) * NF + n]);
            }
            #pragma unroll
            for (int i = 0; i < NTM; ++i) if (i < nt)
                cell_upd(acc[i], cst[i], realu[i], hpos[i], BQ);
            __syncthreads();               // Q complete for next step
        }
    }

    // ==== encoder tail: t = 192..199 (xs slots 0..7) ====
    #pragma unroll
    for (int k = 0; k < 8; ++k) {
        const int P8 = (k & 1) * 128;
        unsigned short* BQ = Bu + ((k & 1) ^ 1) * 1024;

        half8 bh0 = Bsh8[P8 + lane];
        half8 bh1 = Bsh8[P8 + 64 + lane];
        f32x4 acc[NTM];
        #pragma unroll
        for (int i = 0; i < NTM; ++i) if (i < nt) {
            acc[i] = (f32x4){0.f, 0.f, 0.f, 0.f};
            acc[i] = __builtin_amdgcn_mfma_f32_16x16x32_f16(a0[i], bh0, acc[i], 0, 0, 0);
        }
        #pragma unroll
        for (int i = 0; i < NTM; ++i) if (i < nt)
            acc[i] = __builtin_amdgcn_mfma_f32_16x16x32_f16(a1[i], bh1, acc[i], 0, 0, 0);

        const int slot = (k < 7) ? (k + 1) : 7;   // t=199 writes dec_in = x_199
        if (xid >= 0 && xid < 96) {
            int row = xid & 15, n = xid >> 4;
            BQ[row * 8 + n] = h_bits((_Float16)xs[row * 97 + slot * NF + n]);
        }
        #pragma unroll
        for (int i = 0; i < NTM; ++i) if (i < nt)
            cell_upd(acc[i], cst[i], realu[i], hpos[i], BQ);
        __syncthreads();
    }

    // ==== switch to decoder weights (registers only) ====
    #pragma unroll
    for (int i = 0; i < NTM; ++i) if (i < nt) {
        a0[i] = mk8(Wih_d, Whh_d, bih_d, bhh_d, vA_[i], orow_[i], sc_[i], q * 8);
        a1[i] = mk8(Wih_d, Whh_d, bih_d, bhh_d, vA_[i], orow_[i], sc_[i], 32 + q * 8);
    }

    // ==== decoder: 5 steps (t = 200+d; parity d&1) ====
    #pragma unroll
    for (int d = 0; d < TT; ++d) {
        const int P8 = (d & 1) * 128;
        unsigned short* BQ = Bu + ((d & 1) ^ 1) * 1024;

        half8 bh0 = Bsh8[P8 + lane];
        half8 bh1 = Bsh8[P8 + 64 + lane];
        f32x4 acc[NTM];
        #pragma unroll
        for (int i = 0; i < NTM; ++i) if (i < nt) {
            acc[i] = (f32x4){0.f, 0.f, 0.f, 0.f};
            acc[i] = __builtin_amdgcn_mfma_f32_16x16x32_f16(a0[i], bh0, acc[i], 0, 0, 0);
        }
        #pragma unroll
        for (int i = 0; i < NTM; ++i) if (i < nt)
            acc[i] = __builtin_amdgcn_mfma_f32_16x16x32_f16(a1[i], bh1, acc[i], 0, 0, 0);
        #pragma unroll
        for (int i = 0; i < NTM; ++i) if (i < nt)
            cell_upd(acc[i], cst[i], realu[i], hpos[i], BQ);
        __syncthreads();                   // h_t visible in Q

        if (tid < 96) {
            int row = tid & 15, n = tid >> 4;
            float a = bls[n];
            #pragma unroll
            for (int u2 = 0; u2 < HH; ++u2) {
                int kk = NF + u2;
                int pos = ((kk >> 5) * 64 + ((kk >> 3) & 3) * 16 + row) * 8 + (kk & 7);
                a = fmaf(Wls[n * HH + u2], h_f(BQ[pos]), a);
            }
            out[(size_t)(b0 + row) * (TT * NF) + d * NF + n] = a;
            BQ[row * 8 + n] = h_bits((_Float16)a);   // feed back as next x
        }
        __syncthreads();
    }
}

extern "C" void kernel_launch(void* const* d_in, const int* in_sizes, int n_in,
                              void* d_out, int out_size, void* d_ws, size_t ws_size,
                              hipStream_t stream)
{
    const float* seq   = (const float*)d_in[0];
    const float* Wih_e = (const float*)d_in[1];
    const float* Whh_e = (const float*)d_in[2];
    const float* bih_e = (const float*)d_in[3];
    const float* bhh_e = (const float*)d_in[4];
    const float* Wih_d = (const float*)d_in[5];
    const float* Whh_d = (const float*)d_in[6];
    const float* bih_d = (const float*)d_in[7];
    const float* bhh_d = (const float*)d_in[8];
    const float* Wl    = (const float*)d_in[9];
    const float* bl    = (const float*)d_in[10];
    float* out = (float*)d_out;

    dim3 grid(BB / ROWS);   // 1024 blocks -> 4/CU; waves land 1-per-SIMD from
    dim3 block(BLK);        // 4 different blocks = independent streams
    lstm_4w<<<grid, block, 0, stream>>>(seq, Wih_e, Whh_e, bih_e, bhh_e,
                                        Wih_d, Whh_d, bih_d, bhh_d,
                                        Wl, bl, out);
}